// Round 4
// baseline (93.536 us; speedup 1.0000x reference)
//
#include <hip/hip_runtime.h>

#define RR 4
#define LRH 256
#define LRW 256
#define HRH 1024
#define HRW 1024

// lowres tile
#define LTW 32
#define LTH 8
#define LGW (LTW + 2*RR)   // 40
#define LGH (LTH + 2*RR)   // 16

// stencil tile: 32x32 outputs per block, 4 rows per thread
#define STW 32
#define STH 32
#define RPT 4
#define SGW (STW + 2*RR)   // 40
#define SGH (STH + 2*RR)   // 40

// Kernel 1: low-res 9x9 box stats (replication pad = clamp) -> interleaved (A,B)
// Separable: stage (x,y,xy,xx) float4 -> horizontal 9-tap -> vertical 9-tap.
__global__ __launch_bounds__(256) void lowres_coeffs(
    const float* __restrict__ lrx, const float* __restrict__ lry,
    float2* __restrict__ AB)
{
    __shared__ float4 sV[LGH][LGW];   // x, y, xy, xx (padded tile)
    __shared__ float4 sH[LGH][LTW];   // horizontal 9-tap sums

    const int c  = blockIdx.z;
    const int X0 = blockIdx.x * LTW, Y0 = blockIdx.y * LTH;
    const int tid = threadIdx.y * LTW + threadIdx.x;
    const float* px = lrx + c * LRH * LRW;
    const float* py = lry + c * LRH * LRW;

    for (int i = tid; i < LGH * LGW; i += 256) {
        int r = i / LGW, col = i - r * LGW;
        int gy = min(max(Y0 - RR + r, 0), LRH - 1);
        int gx = min(max(X0 - RR + col, 0), LRW - 1);
        float xv = px[gy * LRW + gx];
        float yv = py[gy * LRW + gx];
        sV[r][col] = make_float4(xv, yv, xv * yv, xv * xv);
    }
    __syncthreads();

    for (int i = tid; i < LGH * LTW; i += 256) {
        int r = i / LTW, col = i - r * LTW;
        float4 s = sV[r][col];
        #pragma unroll
        for (int k = 1; k < 9; ++k) {
            float4 v = sV[r][col + k];
            s.x += v.x; s.y += v.y; s.z += v.z; s.w += v.w;
        }
        sH[r][col] = s;
    }
    __syncthreads();

    const int tx = threadIdx.x, ty = threadIdx.y;
    float4 s = sH[ty][tx];
    #pragma unroll
    for (int k = 1; k < 9; ++k) {
        float4 v = sH[ty + k][tx];
        s.x += v.x; s.y += v.y; s.z += v.z; s.w += v.w;
    }
    const float inv81 = 1.0f / 81.0f;
    float mx = s.x * inv81, my = s.y * inv81;
    float cov = s.z * inv81 - mx * my;
    float var = s.w * inv81 - mx * mx;
    float A = cov / (var + 2.0f);
    float B = my - A * mx;
    AB[(c * LRH + Y0 + ty) * LRW + X0 + tx] = make_float2(A, B);
}

// Kernel 2: fused bilinear upsample (align_corners=True) + 8-dir side-window
// stencil + argmin|d| + trunc/clamp. 32x32 tile, 4 rows/thread, coordinate
// LUTs in LDS, register sliding window for the vertical 9-tap.
__global__ __launch_bounds__(256, 4) void stencil_kernel(
    const float2* __restrict__ AB,
    const float* __restrict__ hrx, float* __restrict__ out)
{
    __shared__ float2 sAB[SGH][SGW];  // upsampled (A,B), padded tile (12.8 KB)
    __shared__ float4 sH[SGH][STW];   // hLa,hLb,hRa,hRb (20.5 KB)
    __shared__ int    iLx[SGW];       // lr col index per tile col
    __shared__ float2 wLx[SGW];       // (1-fx, fx)
    __shared__ int    iLyo[SGH];      // lr row offset (iy*LRW) per tile row
    __shared__ float2 wLy[SGH];       // (1-fy, fy)

    const int c  = blockIdx.z;
    const int X0 = blockIdx.x * STW, Y0 = blockIdx.y * STH;
    const int tid = threadIdx.y * STW + threadIdx.x;
    const float2* ABc = AB + c * LRH * LRW;
    const float scale = 255.0f / 1023.0f;  // (src-1)/(out-1)

    // Bilinear coordinate LUTs (40 x-entries, 40 y-entries)
    if (tid < SGW) {
        int gx = min(max(X0 - RR + tid, 0), HRW - 1);
        float t = (float)gx * scale;
        int ix = (int)t; if (ix > LRW - 2) ix = LRW - 2;
        float f = t - (float)ix;
        iLx[tid] = ix;
        wLx[tid] = make_float2(1.0f - f, f);
    } else if (tid >= 64 && tid < 64 + SGH) {
        int r = tid - 64;
        int gy = min(max(Y0 - RR + r, 0), HRH - 1);
        float t = (float)gy * scale;
        int iy = (int)t; if (iy > LRH - 2) iy = LRH - 2;
        float f = t - (float)iy;
        iLyo[r] = iy * LRW;
        wLy[r] = make_float2(1.0f - f, f);
    }
    __syncthreads();

    // Stage upsampled A,B padded tile
    for (int i = tid; i < SGH * SGW; i += 256) {
        int r = i / SGW, col = i - r * SGW;
        const float2* p = ABc + iLyo[r] + iLx[col];
        float2 wy = wLy[r], wx = wLx[col];
        float2 v00 = p[0], v01 = p[1], v10 = p[LRW], v11 = p[LRW + 1];
        float a0 = v00.x * wy.x + v10.x * wy.y;
        float a1 = v01.x * wy.x + v11.x * wy.y;
        float b0 = v00.y * wy.x + v10.y * wy.y;
        float b1 = v01.y * wy.x + v11.y * wy.y;
        sAB[r][col] = make_float2(a0 * wx.x + a1 * wx.y,
                                  b0 * wx.x + b1 * wx.y);
    }
    __syncthreads();

    // Horizontal half-window sums: hL = cols [c..c+4], hR = cols [c+4..c+8]
    for (int i = tid; i < SGH * STW; i += 256) {
        int r = i >> 5, col = i & 31;
        float2 v[9];
        #pragma unroll
        for (int k = 0; k < 9; ++k) v[k] = sAB[r][col + k];
        float hLa = v[0].x + v[1].x + v[2].x + v[3].x + v[4].x;
        float hLb = v[0].y + v[1].y + v[2].y + v[3].y + v[4].y;
        float hRa = v[4].x + v[5].x + v[6].x + v[7].x + v[8].x;
        float hRb = v[4].y + v[5].y + v[6].y + v[7].y + v[8].y;
        sH[r][col] = make_float4(hLa, hLb, hRa, hRb);
    }
    __syncthreads();

    const int tx = threadIdx.x;
    const int base = threadIdx.y * RPT;   // tile row of j=0's window start

    // Load this column's 12 rows of (hL,hR) and 12 center values once.
    float4 h[RPT + 8];
    float2 cv[RPT + 8];
    #pragma unroll
    for (int k = 0; k < RPT + 8; ++k) {
        h[k]  = sH[base + k][tx];
        cv[k] = sAB[base + k][tx + RR];
    }

    // Init vertical sums for j=0: T = rows [0..4], B = rows [4..8]
    float4 T = h[0], B = h[4];
    float2 Tc = cv[0], Bc = cv[4];
    #pragma unroll
    for (int k = 1; k <= 4; ++k) {
        T.x += h[k].x; T.y += h[k].y; T.z += h[k].z; T.w += h[k].w;
        B.x += h[k+4].x; B.y += h[k+4].y; B.z += h[k+4].z; B.w += h[k+4].w;
        Tc.x += cv[k].x; Tc.y += cv[k].y;
        Bc.x += cv[k+4].x; Bc.y += cv[k+4].y;
    }

    const float i45 = 1.0f / 45.0f, i25 = 1.0f / 25.0f;
    const float* hp = hrx + (c * HRH + Y0 + base) * HRW + X0 + tx;
    float* op = out + (c * HRH + Y0 + base) * HRW + X0 + tx;

    #pragma unroll
    for (int j = 0; j < RPT; ++j) {
        float4 C  = h[j + 4];
        float2 Cc = cv[j + 4];
        float xv = hp[j * HRW];

        // d_i = c_i * (S_A * xv + S_B) - xv, folded into 2 fma each
        float d0 = fmaf(i45, fmaf(T.x + B.x - C.x,  xv, T.y + B.y - C.y),  -xv); // L
        float d1 = fmaf(i45, fmaf(T.z + B.z - C.z,  xv, T.w + B.w - C.w),  -xv); // R
        float d2 = fmaf(i45, fmaf(T.x + T.z - Tc.x, xv, T.y + T.w - Tc.y), -xv); // U
        float d3 = fmaf(i45, fmaf(B.x + B.z - Bc.x, xv, B.y + B.w - Bc.y), -xv); // D
        float d4 = fmaf(i25, fmaf(T.x, xv, T.y), -xv);                           // NW
        float d5 = fmaf(i25, fmaf(T.z, xv, T.w), -xv);                           // NE
        float d6 = fmaf(i25, fmaf(B.x, xv, B.y), -xv);                           // SW
        float d7 = fmaf(i25, fmaf(B.z, xv, B.w), -xv);                           // SE

        // Tournament argmin, keep-left on <= (== first-occurrence semantics)
        float a0 = fabsf(d0), a1 = fabsf(d1), a2 = fabsf(d2), a3 = fabsf(d3);
        float a4 = fabsf(d4), a5 = fabsf(d5), a6 = fabsf(d6), a7 = fabsf(d7);
        bool c01 = a0 <= a1; float w01 = c01 ? d0 : d1; float m01 = c01 ? a0 : a1;
        bool c23 = a2 <= a3; float w23 = c23 ? d2 : d3; float m23 = c23 ? a2 : a3;
        bool c45 = a4 <= a5; float w45 = c45 ? d4 : d5; float m45 = c45 ? a4 : a5;
        bool c67 = a6 <= a7; float w67 = c67 ? d6 : d7; float m67 = c67 ? a6 : a7;
        bool cA_ = m01 <= m23; float wA = cA_ ? w01 : w23; float mA = cA_ ? m01 : m23;
        bool cB_ = m45 <= m67; float wB = cB_ ? w45 : w67; float mB = cB_ ? m45 : m67;
        float bd = (mA <= mB) ? wA : wB;

        float res = __builtin_amdgcn_fmed3f(truncf(bd + xv), 0.0f, 255.0f);
        op[j * HRW] = res;

        // Slide window down one row
        if (j < RPT - 1) {
            T.x += h[j+5].x - h[j].x;   T.y += h[j+5].y - h[j].y;
            T.z += h[j+5].z - h[j].z;   T.w += h[j+5].w - h[j].w;
            B.x += h[j+9].x - h[j+4].x; B.y += h[j+9].y - h[j+4].y;
            B.z += h[j+9].z - h[j+4].z; B.w += h[j+9].w - h[j+4].w;
            Tc.x += cv[j+5].x - cv[j].x;   Tc.y += cv[j+5].y - cv[j].y;
            Bc.x += cv[j+9].x - cv[j+4].x; Bc.y += cv[j+9].y - cv[j+4].y;
        }
    }
}

extern "C" void kernel_launch(void* const* d_in, const int* in_sizes, int n_in,
                              void* d_out, int out_size, void* d_ws, size_t ws_size,
                              hipStream_t stream) {
    const float* lrx = (const float*)d_in[0];
    const float* lry = (const float*)d_in[1];
    const float* hrx = (const float*)d_in[2];
    (void)d_in[3]; (void)in_sizes; (void)n_in; (void)out_size; (void)ws_size;

    float2* AB = (float2*)d_ws;                // 3*256*256 float2 = 1.5 MB
    float* outp = (float*)d_out;

    dim3 lblock(LTW, LTH);
    dim3 lgrid(LRW / LTW, LRH / LTH, 3);
    lowres_coeffs<<<lgrid, lblock, 0, stream>>>(lrx, lry, AB);

    dim3 sblock(STW, STH / RPT);
    dim3 sgrid(HRW / STW, HRH / STH, 3);
    stencil_kernel<<<sgrid, sblock, 0, stream>>>(AB, hrx, outp);
}

// Round 5
// 87.740 us; speedup vs baseline: 1.0661x; 1.0661x over previous
//
#include <hip/hip_runtime.h>

#define RR 4
#define LRN 256
#define HRN 1024
#define SCALE (255.0f/1023.0f)

// lowres tile
#define LTW 32
#define LTH 8
#define LGW (LTW + 2*RR)   // 40
#define LGH (LTH + 2*RR)   // 16

// main tile: 32 cols x 64 rows of HR pixels, block (32,8), 8 rows/thread
#define TX 32
#define TYR 64
#define BTH 8
#define NROW (TYR / BTH)   // 8
#define LRC 12             // lr cols staged (span of 32 hr cols + stencil halo)
#define LRR 20             // lr rows staged (span of 64 hr rows + stencil halo)

// Kernel 1: low-res 9x9 box stats (replication pad = clamp) -> interleaved (A,B)
__global__ __launch_bounds__(256) void lowres_coeffs(
    const float* __restrict__ lrx, const float* __restrict__ lry,
    float2* __restrict__ AB)
{
    __shared__ float4 sV[LGH][LGW];   // x, y, xy, xx (padded tile)
    __shared__ float4 sH[LGH][LTW];   // horizontal 9-tap sums

    const int c  = blockIdx.z;
    const int X0 = blockIdx.x * LTW, Y0 = blockIdx.y * LTH;
    const int tid = threadIdx.y * LTW + threadIdx.x;
    const float* px = lrx + c * LRN * LRN;
    const float* py = lry + c * LRN * LRN;

    for (int i = tid; i < LGH * LGW; i += 256) {
        int r = i / LGW, col = i - r * LGW;
        int gy = min(max(Y0 - RR + r, 0), LRN - 1);
        int gx = min(max(X0 - RR + col, 0), LRN - 1);
        float xv = px[gy * LRN + gx];
        float yv = py[gy * LRN + gx];
        sV[r][col] = make_float4(xv, yv, xv * yv, xv * xv);
    }
    __syncthreads();

    for (int i = tid; i < LGH * LTW; i += 256) {
        int r = i / LTW, col = i - r * LTW;
        float4 s = sV[r][col];
        #pragma unroll
        for (int k = 1; k < 9; ++k) {
            float4 v = sV[r][col + k];
            s.x += v.x; s.y += v.y; s.z += v.z; s.w += v.w;
        }
        sH[r][col] = s;
    }
    __syncthreads();

    const int tx = threadIdx.x, ty = threadIdx.y;
    float4 s = sH[ty][tx];
    #pragma unroll
    for (int k = 1; k < 9; ++k) {
        float4 v = sH[ty + k][tx];
        s.x += v.x; s.y += v.y; s.z += v.z; s.w += v.w;
    }
    const float inv81 = 1.0f / 81.0f;
    float mx = s.x * inv81, my = s.y * inv81;
    float cov = s.z * inv81 - mx * my;
    float var = s.w * inv81 - mx * mx;
    float A = cov / (var + 2.0f);
    float B = my - A * mx;
    AB[(c * LRN + Y0 + ty) * LRN + X0 + tx] = make_float2(A, B);
}

// Anchor: lr index of the lowest tap of any pattern at out-coord u.
__device__ inline int anchor_of(int u) {
    int k = min(max(u - 4, 0), HRN - 1);
    float t = (float)k * SCALE;
    int i = (int)t; if (i > LRN - 2) i = LRN - 2;
    return i;
}

// Accumulated 4-tap lr weights for hr taps k0..k1 (clamped), relative to anchor a.
// Effective filter = (box over hr taps) o (bilinear align_corners upsample).
__device__ inline float4 mkw(int k0, int k1, int a) {
    float4 w = make_float4(0.f, 0.f, 0.f, 0.f);
    for (int k = k0; k <= k1; ++k) {
        int kc = min(max(k, 0), HRN - 1);
        float t = (float)kc * SCALE;
        int i = (int)t; if (i > LRN - 2) i = LRN - 2;
        float f = t - (float)i;
        int off = i - a;                 // proven in [0,2]
        float wa = 1.0f - f, wb = f;
        w.x += (off == 0) ? wa : 0.0f;
        w.y += (off == 1) ? wa : ((off == 0) ? wb : 0.0f);
        w.z += (off == 2) ? wa : ((off == 1) ? wb : 0.0f);
        w.w += (off == 2) ? wb : 0.0f;
    }
    return w;
}

// Kernel 2: LR-domain side-window filter. Per block:
//  phase0: per-x / per-y 4-tap weight vectors (T/B/F patterns) + stage lr AB tile
//  phase1: vertical mixes -> sT/sB/sF[row][lrcol] (float2 = A,b)
//  phase2: per pixel: 4-col horizontal combine (L/R/F weights) -> 8 dirs,
//          d = cA*x + cB - x, first-occurrence argmin|d|, trunc, clamp.
__global__ __launch_bounds__(256, 6) void stencil_kernel(
    const float2* __restrict__ AB,
    const float* __restrict__ hrx, float* __restrict__ out)
{
    __shared__ float2 sAB[LRR][LRC];    // staged lr (A,b)
    __shared__ float2 sT[TYR][LRC];     // top-pattern vertical mix
    __shared__ float2 sB[TYR][LRC];     // bottom
    __shared__ float2 sF[TYR][LRC];     // full
    __shared__ float4 sYW[TYR][3];      // per-row weights: T,B,F
    __shared__ int    sYA[TYR];         // per-row anchor rel rowbase
    __shared__ float4 sXW[TX][3];       // per-col weights: L,R,F
    __shared__ int    sXA[TX];          // per-col anchor rel colbase

    const int c  = blockIdx.z;
    const int X0 = blockIdx.x * TX, Y0 = blockIdx.y * TYR;
    const int tid = threadIdx.y * TX + threadIdx.x;
    const float2* ABc = AB + c * LRN * LRN;

    const int rowbase = anchor_of(Y0);
    const int colbase = anchor_of(X0);

    // phase 0a: weight LUTs (x: threads 0..31, y: threads 64..127)
    if (tid < TX) {
        int x = X0 + tid;
        int a = anchor_of(x);
        sXA[tid] = a - colbase;
        sXW[tid][0] = mkw(x - 4, x,     a);   // L
        sXW[tid][1] = mkw(x,     x + 4, a);   // R
        sXW[tid][2] = mkw(x - 4, x + 4, a);   // F
    } else if (tid >= 64 && tid < 64 + TYR) {
        int r = tid - 64;
        int y = Y0 + r;
        int a = anchor_of(y);
        sYA[r] = a - rowbase;
        sYW[r][0] = mkw(y - 4, y,     a);     // T
        sYW[r][1] = mkw(y,     y + 4, a);     // B
        sYW[r][2] = mkw(y - 4, y + 4, a);     // F
    }
    // phase 0b: stage lr AB tile (all threads; 240 positions)
    for (int i = tid; i < LRR * LRC; i += 256) {
        int r = i / LRC, cc = i - r * LRC;
        int gr = min(rowbase + r, LRN - 1);
        int gc = min(colbase + cc, LRN - 1);
        sAB[r][cc] = ABc[gr * LRN + gc];
    }
    __syncthreads();

    // phase 1: vertical mixes, 64 rows x 12 lr cols
    for (int i = tid; i < TYR * LRC; i += 256) {
        int r = i / LRC, cc = i - r * LRC;
        int ra = sYA[r];
        float4 wT = sYW[r][0], wB = sYW[r][1], wF = sYW[r][2];
        float2 v0 = sAB[ra][cc],     v1 = sAB[ra + 1][cc];
        float2 v2 = sAB[ra + 2][cc], v3 = sAB[ra + 3][cc];
        sT[r][cc] = make_float2(wT.x*v0.x + wT.y*v1.x + wT.z*v2.x + wT.w*v3.x,
                                wT.x*v0.y + wT.y*v1.y + wT.z*v2.y + wT.w*v3.y);
        sB[r][cc] = make_float2(wB.x*v0.x + wB.y*v1.x + wB.z*v2.x + wB.w*v3.x,
                                wB.x*v0.y + wB.y*v1.y + wB.z*v2.y + wB.w*v3.y);
        sF[r][cc] = make_float2(wF.x*v0.x + wF.y*v1.x + wF.z*v2.x + wF.w*v3.x,
                                wF.x*v0.y + wF.y*v1.y + wF.z*v2.y + wF.w*v3.y);
    }
    __syncthreads();

    // phase 2: per-pixel horizontal combine + argmin
    const int tx = threadIdx.x, tyw = threadIdx.y;
    const int c0 = sXA[tx];
    const float4 wL = sXW[tx][0], wR = sXW[tx][1], wFh = sXW[tx][2];
    const float i45 = 1.0f / 45.0f, i25 = 1.0f / 25.0f;
    const float* hp = hrx + (c * HRN + Y0 + tyw) * HRN + X0 + tx;
    float*       op = out + (c * HRN + Y0 + tyw) * HRN + X0 + tx;

    #pragma unroll
    for (int j = 0; j < NROW; ++j) {
        const int r = tyw + j * BTH;
        float LA=0,Lb=0, RA=0,Rb=0, UA=0,Ub=0, DA=0,Db=0;
        float NWA=0,NWb=0, NEA=0,NEb=0, SWA=0,SWb=0, SEA=0,SEb=0;
        #pragma unroll
        for (int k = 0; k < 4; ++k) {
            float wl = (k==0)?wL.x:(k==1)?wL.y:(k==2)?wL.z:wL.w;
            float wr = (k==0)?wR.x:(k==1)?wR.y:(k==2)?wR.z:wR.w;
            float wf = (k==0)?wFh.x:(k==1)?wFh.y:(k==2)?wFh.z:wFh.w;
            float2 tv = sT[r][c0 + k];
            float2 bv = sB[r][c0 + k];
            float2 fv = sF[r][c0 + k];
            LA = fmaf(wl, fv.x, LA);   Lb = fmaf(wl, fv.y, Lb);
            RA = fmaf(wr, fv.x, RA);   Rb = fmaf(wr, fv.y, Rb);
            UA = fmaf(wf, tv.x, UA);   Ub = fmaf(wf, tv.y, Ub);
            DA = fmaf(wf, bv.x, DA);   Db = fmaf(wf, bv.y, Db);
            NWA = fmaf(wl, tv.x, NWA); NWb = fmaf(wl, tv.y, NWb);
            NEA = fmaf(wr, tv.x, NEA); NEb = fmaf(wr, tv.y, NEb);
            SWA = fmaf(wl, bv.x, SWA); SWb = fmaf(wl, bv.y, SWb);
            SEA = fmaf(wr, bv.x, SEA); SEb = fmaf(wr, bv.y, SEb);
        }
        float xv = hp[j * BTH * HRN];

        float d0 = fmaf(i45, fmaf(LA,  xv, Lb),  -xv); // L
        float d1 = fmaf(i45, fmaf(RA,  xv, Rb),  -xv); // R
        float d2 = fmaf(i45, fmaf(UA,  xv, Ub),  -xv); // U
        float d3 = fmaf(i45, fmaf(DA,  xv, Db),  -xv); // D
        float d4 = fmaf(i25, fmaf(NWA, xv, NWb), -xv); // NW
        float d5 = fmaf(i25, fmaf(NEA, xv, NEb), -xv); // NE
        float d6 = fmaf(i25, fmaf(SWA, xv, SWb), -xv); // SW
        float d7 = fmaf(i25, fmaf(SEA, xv, SEb), -xv); // SE

        float a0 = fabsf(d0), a1 = fabsf(d1), a2 = fabsf(d2), a3 = fabsf(d3);
        float a4 = fabsf(d4), a5 = fabsf(d5), a6 = fabsf(d6), a7 = fabsf(d7);
        bool c01 = a0 <= a1; float w01 = c01 ? d0 : d1; float m01 = c01 ? a0 : a1;
        bool c23 = a2 <= a3; float w23 = c23 ? d2 : d3; float m23 = c23 ? a2 : a3;
        bool c45 = a4 <= a5; float w45 = c45 ? d4 : d5; float m45 = c45 ? a4 : a5;
        bool c67 = a6 <= a7; float w67 = c67 ? d6 : d7; float m67 = c67 ? a6 : a7;
        bool cA_ = m01 <= m23; float wA = cA_ ? w01 : w23; float mA = cA_ ? m01 : m23;
        bool cB_ = m45 <= m67; float wB_ = cB_ ? w45 : w67; float mB = cB_ ? m45 : m67;
        float bd = (mA <= mB) ? wA : wB_;

        float res = __builtin_amdgcn_fmed3f(truncf(bd + xv), 0.0f, 255.0f);
        op[j * BTH * HRN] = res;
    }
}

extern "C" void kernel_launch(void* const* d_in, const int* in_sizes, int n_in,
                              void* d_out, int out_size, void* d_ws, size_t ws_size,
                              hipStream_t stream) {
    const float* lrx = (const float*)d_in[0];
    const float* lry = (const float*)d_in[1];
    const float* hrx = (const float*)d_in[2];
    (void)d_in[3]; (void)in_sizes; (void)n_in; (void)out_size; (void)ws_size;

    float2* AB = (float2*)d_ws;                // 3*256*256 float2 = 1.5 MB
    float* outp = (float*)d_out;

    dim3 lblock(LTW, LTH);
    dim3 lgrid(LRN / LTW, LRN / LTH, 3);
    lowres_coeffs<<<lgrid, lblock, 0, stream>>>(lrx, lry, AB);

    dim3 sblock(TX, BTH);
    dim3 sgrid(HRN / TX, HRN / TYR, 3);
    stencil_kernel<<<sgrid, sblock, 0, stream>>>(AB, hrx, outp);
}

// Round 6
// 85.229 us; speedup vs baseline: 1.0975x; 1.0295x over previous
//
#include <hip/hip_runtime.h>

#define RR 4
#define LRN 256
#define HRN 1024
#define SCALE (255.0f/1023.0f)

// main tile: 32 cols x 64 rows of HR pixels, block (32,8), 8 rows/thread
#define TX 32
#define TYR 64
#define BTH 8
#define NROW (TYR / BTH)   // 8
#define LRC 12             // lr cols of AB needed (span of 32 hr cols + halo)
#define LRR 20             // lr rows of AB needed (span of 64 hr rows + halo)
#define GC (LRC + 8)       // 20  staged lr input cols (box halo)
#define GR (LRR + 8)       // 28  staged lr input rows

typedef float v2 __attribute__((ext_vector_type(2)));

// Anchor: lr index of the lowest tap of any pattern at out-coord u.
__device__ inline int anchor_of(int u) {
    int k = min(max(u - 4, 0), HRN - 1);
    float t = (float)k * SCALE;
    int i = (int)t; if (i > LRN - 2) i = LRN - 2;
    return i;
}

// Accumulated 4-tap lr weights for hr taps k0..k1 (clamped), relative to anchor a.
// Effective filter = (box over hr taps) o (bilinear align_corners upsample).
__device__ inline float4 mkw(int k0, int k1, int a) {
    float4 w = make_float4(0.f, 0.f, 0.f, 0.f);
    for (int k = k0; k <= k1; ++k) {
        int kc = min(max(k, 0), HRN - 1);
        float t = (float)kc * SCALE;
        int i = (int)t; if (i > LRN - 2) i = LRN - 2;
        float f = t - (float)i;
        int off = i - a;                 // in [0,2]
        float wa = 1.0f - f, wb = f;
        w.x += (off == 0) ? wa : 0.0f;
        w.y += (off == 1) ? wa : ((off == 0) ? wb : 0.0f);
        w.z += (off == 2) ? wa : ((off == 1) ? wb : 0.0f);
        w.w += (off == 2) ? wb : 0.0f;
    }
    return w;
}

// Single fused kernel:
//  A: stage lr (x,y,xy,xx) region (GRxGC) with clamped coords (rep-pad)
//  B: horizontal 9-tap box sums
//  C: vertical 9-tap + guided-filter finalize -> sAB (A,b) per lr cell
//  D: per-hr-row vertical 4-tap mixes (T/B/F) -> sT/sV_/sF planes
//  E: per-pixel 4-col horizontal combine (L/R/F) -> 8 dirs, argmin|d|, trunc, clamp
__global__ __launch_bounds__(256, 6) void fused_kernel(
    const float* __restrict__ lrx, const float* __restrict__ lry,
    const float* __restrict__ hrx, float* __restrict__ out)
{
    // region1 aliased: phases A-C use sV(8960)+sHS(5376)=14336 B;
    // phases D-E use sT/sBm/sF = 3*6144 = 18432 B.
    __shared__ alignas(16) char region1[18432];
    float4 (*sV)[GC]  = reinterpret_cast<float4(*)[GC]>(region1);
    float4 (*sHS)[LRC] = reinterpret_cast<float4(*)[LRC]>(region1 + GR * GC * 16);
    v2 (*sT)[LRC]  = reinterpret_cast<v2(*)[LRC]>(region1);
    v2 (*sBm)[LRC] = reinterpret_cast<v2(*)[LRC]>(region1 + 6144);
    v2 (*sF)[LRC]  = reinterpret_cast<v2(*)[LRC]>(region1 + 12288);

    __shared__ v2     sAB[LRR][LRC];    // lr (A,b)
    __shared__ float4 sYW[TYR][3];      // per-row weights: T,B,F
    __shared__ int    sYA[TYR];         // per-row anchor rel rowbase
    __shared__ float4 sXW[TX][3];       // per-col weights: L,R,F
    __shared__ int    sXA[TX];          // per-col anchor rel colbase

    const int c  = blockIdx.z;
    const int X0 = blockIdx.x * TX, Y0 = blockIdx.y * TYR;
    const int tid = threadIdx.y * TX + threadIdx.x;
    const float* px = lrx + c * LRN * LRN;
    const float* py = lry + c * LRN * LRN;

    const int rowbase = anchor_of(Y0);
    const int colbase = anchor_of(X0);

    // phase 0: weight LUTs (x: threads 0..31, y: threads 64..127)
    if (tid < TX) {
        int x = X0 + tid;
        int a = anchor_of(x);
        sXA[tid] = a - colbase;
        sXW[tid][0] = mkw(x - 4, x,     a);   // L
        sXW[tid][1] = mkw(x,     x + 4, a);   // R
        sXW[tid][2] = mkw(x - 4, x + 4, a);   // F
    } else if (tid >= 64 && tid < 64 + TYR) {
        int r = tid - 64;
        int y = Y0 + r;
        int a = anchor_of(y);
        sYA[r] = a - rowbase;
        sYW[r][0] = mkw(y - 4, y,     a);     // T
        sYW[r][1] = mkw(y,     y + 4, a);     // B
        sYW[r][2] = mkw(y - 4, y + 4, a);     // F
    }

    // phase A: stage lr stats region (GR x GC), coords clamped (rep-pad)
    for (int i = tid; i < GR * GC; i += 256) {
        int r = i / GC, cc = i - r * GC;
        int gy = min(max(rowbase - 4 + r, 0), LRN - 1);
        int gx = min(max(colbase - 4 + cc, 0), LRN - 1);
        float xv = px[gy * LRN + gx];
        float yv = py[gy * LRN + gx];
        sV[r][cc] = make_float4(xv, yv, xv * yv, xv * xv);
    }
    __syncthreads();

    // phase B: horizontal 9-tap sums (GR rows x LRC cols)
    for (int i = tid; i < GR * LRC; i += 256) {
        int r = i / LRC, cc = i - r * LRC;
        float4 s = sV[r][cc];
        #pragma unroll
        for (int k = 1; k < 9; ++k) {
            float4 v = sV[r][cc + k];
            s.x += v.x; s.y += v.y; s.z += v.z; s.w += v.w;
        }
        sHS[r][cc] = s;
    }
    __syncthreads();

    // phase C: vertical 9-tap + finalize A,b (LRR x LRC)
    for (int i = tid; i < LRR * LRC; i += 256) {
        int r = i / LRC, cc = i - r * LRC;
        float4 s = sHS[r][cc];
        #pragma unroll
        for (int k = 1; k < 9; ++k) {
            float4 v = sHS[r + k][cc];
            s.x += v.x; s.y += v.y; s.z += v.z; s.w += v.w;
        }
        const float inv81 = 1.0f / 81.0f;
        float mx = s.x * inv81, my = s.y * inv81;
        float cov = s.z * inv81 - mx * my;
        float var = s.w * inv81 - mx * mx;
        float A = cov / (var + 2.0f);
        float B = my - A * mx;
        v2 ab; ab.x = A; ab.y = B;
        sAB[r][cc] = ab;
    }
    __syncthreads();   // sV/sHS dead after this; region1 reused for sT/sBm/sF

    // phase D: vertical 4-tap mixes, TYR rows x LRC lr cols
    for (int i = tid; i < TYR * LRC; i += 256) {
        int r = i / LRC, cc = i - r * LRC;
        int ra = sYA[r];
        float4 wT = sYW[r][0], wB = sYW[r][1], wF = sYW[r][2];
        v2 v0 = sAB[ra][cc],     v1 = sAB[ra + 1][cc];
        v2 v2_ = sAB[ra + 2][cc], v3 = sAB[ra + 3][cc];
        v2 t, b, f;
        t = v0 * wT.x; t = __builtin_elementwise_fma((v2)(wT.y), v1, t);
        t = __builtin_elementwise_fma((v2)(wT.z), v2_, t);
        t = __builtin_elementwise_fma((v2)(wT.w), v3, t);
        b = v0 * wB.x; b = __builtin_elementwise_fma((v2)(wB.y), v1, b);
        b = __builtin_elementwise_fma((v2)(wB.z), v2_, b);
        b = __builtin_elementwise_fma((v2)(wB.w), v3, b);
        f = v0 * wF.x; f = __builtin_elementwise_fma((v2)(wF.y), v1, f);
        f = __builtin_elementwise_fma((v2)(wF.z), v2_, f);
        f = __builtin_elementwise_fma((v2)(wF.w), v3, f);
        sT[r][cc] = t; sBm[r][cc] = b; sF[r][cc] = f;
    }
    __syncthreads();

    // phase E: per-pixel horizontal combine + argmin
    const int tx = threadIdx.x, tyw = threadIdx.y;
    const int c0 = sXA[tx];
    const float4 wL = sXW[tx][0], wR = sXW[tx][1], wFh = sXW[tx][2];
    const float i45 = 1.0f / 45.0f, i25 = 1.0f / 25.0f;
    const float* hp = hrx + (c * HRN + Y0 + tyw) * HRN + X0 + tx;
    float*       op = out + (c * HRN + Y0 + tyw) * HRN + X0 + tx;

    #pragma unroll
    for (int j = 0; j < NROW; ++j) {
        const int r = tyw + j * BTH;
        v2 aL = 0, aR = 0, aU = 0, aD = 0;
        v2 aNW = 0, aNE = 0, aSW = 0, aSE = 0;
        #pragma unroll
        for (int k = 0; k < 4; ++k) {
            float wl = (k==0)?wL.x:(k==1)?wL.y:(k==2)?wL.z:wL.w;
            float wr = (k==0)?wR.x:(k==1)?wR.y:(k==2)?wR.z:wR.w;
            float wf = (k==0)?wFh.x:(k==1)?wFh.y:(k==2)?wFh.z:wFh.w;
            v2 tv = sT[r][c0 + k];
            v2 bv = sBm[r][c0 + k];
            v2 fv = sF[r][c0 + k];
            aL  = __builtin_elementwise_fma((v2)(wl), fv, aL);
            aR  = __builtin_elementwise_fma((v2)(wr), fv, aR);
            aU  = __builtin_elementwise_fma((v2)(wf), tv, aU);
            aD  = __builtin_elementwise_fma((v2)(wf), bv, aD);
            aNW = __builtin_elementwise_fma((v2)(wl), tv, aNW);
            aNE = __builtin_elementwise_fma((v2)(wr), tv, aNE);
            aSW = __builtin_elementwise_fma((v2)(wl), bv, aSW);
            aSE = __builtin_elementwise_fma((v2)(wr), bv, aSE);
        }
        float xv = hp[j * BTH * HRN];

        float d0 = fmaf(i45, fmaf(aL.x,  xv, aL.y),  -xv); // L
        float d1 = fmaf(i45, fmaf(aR.x,  xv, aR.y),  -xv); // R
        float d2 = fmaf(i45, fmaf(aU.x,  xv, aU.y),  -xv); // U
        float d3 = fmaf(i45, fmaf(aD.x,  xv, aD.y),  -xv); // D
        float d4 = fmaf(i25, fmaf(aNW.x, xv, aNW.y), -xv); // NW
        float d5 = fmaf(i25, fmaf(aNE.x, xv, aNE.y), -xv); // NE
        float d6 = fmaf(i25, fmaf(aSW.x, xv, aSW.y), -xv); // SW
        float d7 = fmaf(i25, fmaf(aSE.x, xv, aSE.y), -xv); // SE

        float a0 = fabsf(d0), a1 = fabsf(d1), a2 = fabsf(d2), a3 = fabsf(d3);
        float a4 = fabsf(d4), a5 = fabsf(d5), a6 = fabsf(d6), a7 = fabsf(d7);
        bool c01 = a0 <= a1; float w01 = c01 ? d0 : d1; float m01 = c01 ? a0 : a1;
        bool c23 = a2 <= a3; float w23 = c23 ? d2 : d3; float m23 = c23 ? a2 : a3;
        bool c45 = a4 <= a5; float w45 = c45 ? d4 : d5; float m45 = c45 ? a4 : a5;
        bool c67 = a6 <= a7; float w67 = c67 ? d6 : d7; float m67 = c67 ? a6 : a7;
        bool cA_ = m01 <= m23; float wA = cA_ ? w01 : w23; float mA = cA_ ? m01 : m23;
        bool cB_ = m45 <= m67; float wB_ = cB_ ? w45 : w67; float mB = cB_ ? m45 : m67;
        float bd = (mA <= mB) ? wA : wB_;

        float res = __builtin_amdgcn_fmed3f(truncf(bd + xv), 0.0f, 255.0f);
        op[j * BTH * HRN] = res;
    }
}

extern "C" void kernel_launch(void* const* d_in, const int* in_sizes, int n_in,
                              void* d_out, int out_size, void* d_ws, size_t ws_size,
                              hipStream_t stream) {
    const float* lrx = (const float*)d_in[0];
    const float* lry = (const float*)d_in[1];
    const float* hrx = (const float*)d_in[2];
    (void)d_in[3]; (void)in_sizes; (void)n_in; (void)out_size;
    (void)d_ws; (void)ws_size;

    float* outp = (float*)d_out;
    dim3 block(TX, BTH);
    dim3 grid(HRN / TX, HRN / TYR, 3);
    fused_kernel<<<grid, block, 0, stream>>>(lrx, lry, hrx, outp);
}